// Round 27
// baseline (17.073 us; speedup 1.0000x reference)
//
#include <hip/hip_runtime.h>
#include <math.h>

#define SD 39
#define BLOCK 1024   // 16 waves/block, 2 blocks/CU -> 32 waves/CU = 8/SIMD

typedef _Float16 half8 __attribute__((ext_vector_type(8)));
typedef __fp16 h2v __attribute__((ext_vector_type(2)));   // cvt_pkrtz's type
typedef float f32x16 __attribute__((ext_vector_type(16)));

// ---- 32x32x16 MFMA formulation (R22/R25, verified) ----
// batch col = lane&31 through all layers; C layout col=lane&31,
// row=(reg&3)+8*(reg>>2)+4*(lane>>5). Slot space (h=lane>>5, j=0..7);
// kappa(slot->k) baked identically into weight frags (prologue) and data
// repacks (chain). Biases ride spare K-slots via constant-1 data column.
// R27 (=R26 fixed): f32->f16 glue via v_cvt_pkrtz_f16_f32 (1 instr per 2
// elems). ReLU stays in f32 (fmaxf) -- semantics identical to R25 except
// RTZ rounding on the f16 convert.
#define NFRAG 20
#define DW_QPE (NFRAG * 256)
#define DW_TOT (DW_QPE + 4)        // 20.5 KB LDS

#define MFMA32(W, X, C) __builtin_amdgcn_mfma_f32_32x32x16_f16((W), (X), (C), 0, 0, 0)

union H8 { half8 v8; h2v v2[4]; };

static __device__ __forceinline__ h2v pk(float a, float b) {
    return __builtin_amdgcn_cvt_pkrtz(a, b);
}
static __device__ __forceinline__ h2v pkr(float a, float b) {   // relu+pack
    return __builtin_amdgcn_cvt_pkrtz(fmaxf(a, 0.0f), fmaxf(b, 0.0f));
}

__global__ __launch_bounds__(BLOCK)
__attribute__((amdgpu_waves_per_eu(8)))   // VGPR<=64 -> 8 waves/SIMD
void qnet_kernel(const float* __restrict__ state,
                 const float* __restrict__ ew1, const float* __restrict__ eb1,
                 const float* __restrict__ ew2, const float* __restrict__ eb2,
                 const float* __restrict__ ew3, const float* __restrict__ eb3,
                 const float* __restrict__ qp,
                 const float* __restrict__ dw1, const float* __restrict__ db1,
                 const float* __restrict__ dw2, const float* __restrict__ db2,
                 const float* __restrict__ dw3, const float* __restrict__ db3,
                 float* __restrict__ out, long long nrows)
{
    __shared__ __align__(16) float lf[DW_TOT];
    _Float16* wh = (_Float16*)lf;
    const int tid = threadIdx.x;

    // ---- fragment build (10 iters/thread; identical to R22) ----
    for (int i = tid; i < NFRAG * 512; i += BLOCK) {
        int f = i >> 9, l = (i >> 3) & 63, j = i & 7;
        int h = l >> 5, m = l & 31;
        float v = 0.0f;
        if (f < 6) {                         // L1
            int mt = f / 3, s = f % 3;
            int o = mt * 32 + m, k = s * 16 + 8 * h + j;
            v = (k < SD) ? ew1[o * SD + k] : (k == SD ? eb1[o] : 0.0f);
        } else if (f < 11) {                 // L2
            int s = f - 6;
            if (s < 4) {
                int r = (s & 1) * 8 + j;
                int o1 = (r & 3) + 8 * (r >> 2) + 4 * h + 32 * (s >> 1);
                v = ew2[m * 64 + o1];
            } else v = (h == 0 && j == 0) ? eb2[m] : 0.0f;
        } else if (f < 14) {                 // L3
            int s = f - 11;
            if (s < 2) {
                int r = s * 8 + j;
                int o2 = (r & 3) + 8 * (r >> 2) + 4 * h;
                v = (m < 4) ? ew3[m * 32 + o2] : 0.0f;
            } else v = (h == 0 && j == 0 && m < 4) ? eb3[m] : 0.0f;
        } else if (f == 14) {                // D1
            v = (h == 0) ? (j < 4 ? dw1[m * 4 + j]
                                  : (j == 4 ? db1[m] : 0.0f)) : 0.0f;
        } else if (f < 18) {                 // D2
            int s = f - 15;
            if (s < 2) {
                int r = s * 8 + j;
                int k1 = (r & 3) + 8 * (r >> 2) + 4 * h;
                v = (m < 16) ? dw2[m * 32 + k1] : 0.0f;
            } else v = (h == 0 && j == 0 && m < 16) ? db2[m] : 0.0f;
        } else {                             // D3
            int s = f - 18;
            if (s == 0) {
                int k = (j & 3) + 8 * (j >> 2) + 4 * h;
                v = (m < 8) ? dw3[m * 16 + k] : 0.0f;
            } else v = (h == 0 && j == 0 && m < 8) ? db3[m] : 0.0f;
        }
        wh[i] = (_Float16)v;
    }
    for (int i = tid; i < 4; i += BLOCK) lf[DW_QPE + i] = qp[2 * i];
    __syncthreads();

    const int lane = tid & 63;
    const int h = lane >> 5, c = lane & 31;
    const long long gwave = (long long)blockIdx.x * (BLOCK / 64) + (tid >> 6);
    const long long R = gwave * 32;                    // 32 rows per wave
    if (R >= nrows) return;

    const half8* hws = (const half8*)lf;
    const float* qpep = lf + DW_QPE;

    // ---- state B-fragments via packed converts ----
    const float* sp = state + (R + c) * SD;
    float4 r0 = *(const float4*)(sp + 8 * h);
    float4 r1 = *(const float4*)(sp + 8 * h + 4);
    float4 r2 = *(const float4*)(sp + 16 + 8 * h);
    float4 r3 = *(const float4*)(sp + 20 + 8 * h);
    float4 r4 = make_float4(0.f, 0.f, 0.f, 0.f);
    float4 r5 = make_float4(0.f, 0.f, 0.f, 0.f);
    if (h == 0) {                       // cols 32..38 (h=1 slots are k>=40 -> w=0)
        r4 = *(const float4*)(sp + 32);
        r5 = *(const float4*)(sp + 35); // ends exactly at col 38 (in-bounds)
    }
    H8 xf0, xf1, xf2;
    xf0.v2[0] = pk(r0.x, r0.y); xf0.v2[1] = pk(r0.z, r0.w);
    xf0.v2[2] = pk(r1.x, r1.y); xf0.v2[3] = pk(r1.z, r1.w);
    xf1.v2[0] = pk(r2.x, r2.y); xf1.v2[1] = pk(r2.z, r2.w);
    xf1.v2[2] = pk(r3.x, r3.y); xf1.v2[3] = pk(r3.z, r3.w);
    xf2.v2[0] = pk(r4.x, r4.y); xf2.v2[1] = pk(r4.z, r4.w);
    xf2.v2[2] = pk(r5.y, r5.z); xf2.v2[3] = pk(r5.w, 1.0f);  // k=39 bias col

    f32x16 z;
    #pragma unroll
    for (int i = 0; i < 16; i++) z[i] = 0.0f;

    H8 hbias;
    hbias.v2[0] = pk((h == 0) ? 1.0f : 0.0f, 0.0f);
    hbias.v2[1] = pk(0.0f, 0.0f);
    hbias.v2[2] = hbias.v2[1]; hbias.v2[3] = hbias.v2[1];

    // ---- L1 tile a: fold into c2 immediately (c1 regs die before tile b) ----
    f32x16 c1 = z;
    c1 = MFMA32(hws[0 * 64 + lane], xf0.v8, c1);
    c1 = MFMA32(hws[1 * 64 + lane], xf1.v8, c1);
    c1 = MFMA32(hws[2 * 64 + lane], xf2.v8, c1);
    H8 hb0, hb1;
    #pragma unroll
    for (int k = 0; k < 4; k++) {
        hb0.v2[k] = pkr(c1[2 * k], c1[2 * k + 1]);
        hb1.v2[k] = pkr(c1[8 + 2 * k], c1[9 + 2 * k]);
    }
    f32x16 c2 = z;
    c2 = MFMA32(hws[6 * 64 + lane], hb0.v8, c2);
    c2 = MFMA32(hws[7 * 64 + lane], hb1.v8, c2);

    // ---- L1 tile b (c1 regs reused) ----
    c1 = z;
    c1 = MFMA32(hws[3 * 64 + lane], xf0.v8, c1);
    c1 = MFMA32(hws[4 * 64 + lane], xf1.v8, c1);
    c1 = MFMA32(hws[5 * 64 + lane], xf2.v8, c1);
    #pragma unroll
    for (int k = 0; k < 4; k++) {
        hb0.v2[k] = pkr(c1[2 * k], c1[2 * k + 1]);
        hb1.v2[k] = pkr(c1[8 + 2 * k], c1[9 + 2 * k]);
    }
    c2 = MFMA32(hws[8 * 64 + lane],  hb0.v8,   c2);
    c2 = MFMA32(hws[9 * 64 + lane],  hb1.v8,   c2);
    c2 = MFMA32(hws[10 * 64 + lane], hbias.v8, c2);

    H8 h30, h31;
    #pragma unroll
    for (int k = 0; k < 4; k++) {
        h30.v2[k] = pkr(c2[2 * k], c2[2 * k + 1]);
        h31.v2[k] = pkr(c2[8 + 2 * k], c2[9 + 2 * k]);
    }

    // ---- L3: 2 data steps + bias ----
    f32x16 e = z;
    e = MFMA32(hws[11 * 64 + lane], h30.v8,   e);
    e = MFMA32(hws[12 * 64 + lane], h31.v8,   e);
    e = MFMA32(hws[13 * 64 + lane], hbias.v8, e);

    // ---- quantum: ev_i = prod_{j<=i} cos(tanh(e_j)*pi + qp[2j]) ----
    // (RZ cancels under Z-measure; CNOT chain -> bit i = b0^..^bi)
    float ev[4]; float cp = 1.0f;
    #pragma unroll
    for (int r = 0; r < 4; r++) {
        float ex = __expf(2.0f * e[r]);
        float t = 1.0f - 2.0f / (ex + 1.0f);      // tanh
        cp *= __cosf(fmaf(t, 3.14159265358979323846f, qpep[r]));
        ev[r] = cp;
    }
    H8 evf;
    if (h == 0) {
        evf.v2[0] = pk(ev[0], ev[1]);
        evf.v2[1] = pk(ev[2], ev[3]);
        evf.v2[2] = pk(1.0f, 0.0f);               // db1 slot
    } else {
        evf.v2[0] = pk(0.0f, 0.0f);
        evf.v2[1] = evf.v2[0];
        evf.v2[2] = evf.v2[0];
    }
    evf.v2[3] = pk(0.0f, 0.0f);

    // ---- D1: single MFMA ----
    f32x16 cd1 = MFMA32(hws[14 * 64 + lane], evf.v8, z);
    H8 hd0, hd1;
    #pragma unroll
    for (int k = 0; k < 4; k++) {
        hd0.v2[k] = pkr(cd1[2 * k], cd1[2 * k + 1]);
        hd1.v2[k] = pkr(cd1[8 + 2 * k], cd1[9 + 2 * k]);
    }

    // ---- D2: 2 data steps + bias ----
    f32x16 cd2 = z;
    cd2 = MFMA32(hws[15 * 64 + lane], hd0.v8,   cd2);
    cd2 = MFMA32(hws[16 * 64 + lane], hd1.v8,   cd2);
    cd2 = MFMA32(hws[17 * 64 + lane], hbias.v8, cd2);

    H8 hd3;
    #pragma unroll
    for (int k = 0; k < 4; k++) hd3.v2[k] = pkr(cd2[2 * k], cd2[2 * k + 1]);

    // ---- D3: 1 data step + bias; dims 4h+0..3 in regs 0..3 ----
    f32x16 o = z;
    o = MFMA32(hws[18 * 64 + lane], hd3.v8,   o);
    o = MFMA32(hws[19 * 64 + lane], hbias.v8, o);

    float4* op = (float4*)(out + (R + c) * 8 + 4 * h);   // full-wave store
    *op = make_float4(o[0], o[1], o[2], o[3]);
}

extern "C" void kernel_launch(void* const* d_in, const int* in_sizes, int n_in,
                              void* d_out, int out_size, void* d_ws, size_t ws_size,
                              hipStream_t stream) {
    const float* state = (const float*)d_in[0];
    const float* ew1 = (const float*)d_in[1];
    const float* eb1 = (const float*)d_in[2];
    const float* ew2 = (const float*)d_in[3];
    const float* eb2 = (const float*)d_in[4];
    const float* ew3 = (const float*)d_in[5];
    const float* eb3 = (const float*)d_in[6];
    const float* qp  = (const float*)d_in[7];
    const float* dw1 = (const float*)d_in[8];
    const float* db1 = (const float*)d_in[9];
    const float* dw2 = (const float*)d_in[10];
    const float* db2 = (const float*)d_in[11];
    const float* dw3 = (const float*)d_in[12];
    const float* db3 = (const float*)d_in[13];
    float* out = (float*)d_out;

    const long long B = in_sizes[0] / SD;              // 262144
    // 8192 waves x 32 rows; 512 blocks x 16 waves, 2 blocks/CU.
    const int blocks = (int)((B / 32 + (BLOCK / 64) - 1) / (BLOCK / 64));
    hipLaunchKernelGGL(qnet_kernel, dim3(blocks), dim3(BLOCK), 0, stream,
                       state, ew1, eb1, ew2, eb2, ew3, eb3, qp,
                       dw1, db1, dw2, db2, dw3, db3, out, B);
}